// Round 8
// baseline (316.441 us; speedup 1.0000x reference)
//
#include <hip/hip_runtime.h>
#include <stdint.h>

typedef unsigned short u16;
typedef __bf16 bf16x8 __attribute__((ext_vector_type(8)));
typedef float f32x4 __attribute__((ext_vector_type(4)));

__device__ __forceinline__ u16 f2bf(float f) {
  union { float f; uint32_t u; } x; x.f = f;
  uint32_t u = x.u;
  u += 0x7fffu + ((u >> 16) & 1u);   // round-to-nearest-even
  return (u16)(u >> 16);
}
__device__ __forceinline__ float bf2f(uint32_t lo16) {
  union { uint32_t u; float f; } x; x.u = lo16 << 16; return x.f;
}

__device__ __forceinline__ void async_load16(const u16* g, u16* l) {
  __builtin_amdgcn_global_load_lds(
      (const __attribute__((address_space(1))) void*)g,
      (__attribute__((address_space(3))) void*)l,
      16, 0, 0);
}

// ---------------- prep_all: sigmoid(beta) + weight converts + x convert + flag zero ----
__global__ __launch_bounds__(256) void prep_all(const float* __restrict__ x,
                                                const float* __restrict__ Wq,
                                                const float* __restrict__ Wfc,
                                                const float* __restrict__ braw,
                                                u16* __restrict__ xb,
                                                u16* __restrict__ wqb,
                                                u16* __restrict__ wfcb,
                                                float* __restrict__ beta,
                                                uint32_t* __restrict__ flags) {
  int gid = blockIdx.x * 256 + threadIdx.x;
  if (gid < 512) flags[gid] = 0;     // scan sync flags (visible via stream ordering)
  if (gid < 1024) beta[gid] = 1.0f / (1.0f + expf(-braw[gid]));
  if (gid < 131072) {
    const int HH = 1024 * 1024;
    int i = gid * 16;
    const float* src = (i < HH) ? (Wq + i) : (Wfc + (i - HH));
    u16* dst = (i < HH) ? (wqb + i) : (wfcb + (i - HH));
#pragma unroll
    for (int c = 0; c < 4; c++) {
      float4 v = *(const float4*)(src + c * 4);
      ushort4 o = {f2bf(v.x), f2bf(v.y), f2bf(v.z), f2bf(v.w)};
      *(ushort4*)(dst + c * 4) = o;
    }
  }
  {
    int i = gid * 8;
    float4 a = *(const float4*)(x + i);
    float4 b = *(const float4*)(x + i + 4);
    ushort4 o0 = {f2bf(a.x), f2bf(a.y), f2bf(a.z), f2bf(a.w)};
    ushort4 o1 = {f2bf(b.x), f2bf(b.y), f2bf(b.z), f2bf(b.w)};
    *(ushort4*)(xb + i) = o0;
    *(ushort4*)(xb + i + 4) = o1;
  }
}

// ---------------- GEMM: C = A (MxK bf16) * B^T (NxK bf16) + bias ----------------
// r6-proven: 128x128 tile, BK=64 (16 K-iters), 4 waves (2x2), each wave 64x64 via
// 4x4 mfma_f32_16x16x32_bf16, two 32-k sub-steps/iter. XOR-8 LDS swizzle keeps
// ds_read_b128 conflict-free. EXPLICIT s_waitcnt(0) before the post-staging barrier
// (r3 raced without it; r4/r6 validated through graph-replay revalidation).
template <int RELU, int OUTBF>
__global__ __launch_bounds__(256) void gemm_bt(const u16* __restrict__ A,
                                               const u16* __restrict__ B,
                                               const float* __restrict__ bias,
                                               void* __restrict__ Cout,
                                               int M, int N, int K) {
  __shared__ u16 As[128 * 64];
  __shared__ u16 Bs[128 * 64];

  const int tid  = threadIdx.x;
  const int lane = tid & 63;

  // XCD-aware remap (grid = 1024 = 128 m-tiles x 8 n-tiles; xcd = L % 8):
  // XCD c owns m-tiles [16c,16c+16) x all 8 n-tiles -> ~3 MB L2 working set.
  const int L  = blockIdx.x;
  const int xc = L & 7;
  const int k8 = L >> 3;
  const int tile_n = (k8 & 7) * 128;
  const int tile_m = ((xc << 4) | (k8 >> 3)) * 128;

  const int wm = ((tid >> 7) & 1) * 64;
  const int wn = ((tid >> 6) & 1) * 64;

  // staging: per issue, 256 threads cover 32 rows x 8 chunks(16B). Thread tid:
  // row = tid>>3, dest chunk = tid&7, source global chunk = (tid&7) ^ (row&7).
  const int srow   = tid >> 3;
  const int schunk = (tid & 7) ^ ((tid >> 3) & 7);
  u16* ldsA = &As[((tid >> 6) * 8) * 64];
  u16* ldsB = &Bs[((tid >> 6) * 8) * 64];

  const u16* gA = A + (size_t)(tile_m + srow) * K + schunk * 8;
  const u16* gB = B + (size_t)(tile_n + srow) * K + schunk * 8;

  f32x4 acc[4][4];
#pragma unroll
  for (int i = 0; i < 4; i++)
#pragma unroll
    for (int j = 0; j < 4; j++) acc[i][j] = (f32x4){0.f, 0.f, 0.f, 0.f};

  const int lrow = lane & 15;
  const int kq   = lane >> 4;

  for (int k0 = 0; k0 < K; k0 += 64) {
    __syncthreads();
#pragma unroll
    for (int i = 0; i < 4; i++) {
      async_load16(gA + (size_t)(i * 32) * K + k0, ldsA + i * 32 * 64);
      async_load16(gB + (size_t)(i * 32) * K + k0, ldsB + i * 32 * 64);
    }
    __builtin_amdgcn_s_waitcnt(0);  // contractual LDS-DMA drain before publish
    __syncthreads();

#pragma unroll
    for (int js = 0; js < 2; js++) {
      const int cc = ((kq + 4 * js) ^ (lane & 7)) << 3;
      bf16x8 a[4], b[4];
#pragma unroll
      for (int i = 0; i < 4; i++)
        a[i] = *(const bf16x8*)&As[(wm + i * 16 + lrow) * 64 + cc];
#pragma unroll
      for (int j = 0; j < 4; j++)
        b[j] = *(const bf16x8*)&Bs[(wn + j * 16 + lrow) * 64 + cc];
#pragma unroll
      for (int i = 0; i < 4; i++)
#pragma unroll
        for (int j = 0; j < 4; j++)
          acc[i][j] = __builtin_amdgcn_mfma_f32_16x16x32_bf16(a[i], b[j], acc[i][j], 0, 0, 0);
    }
  }

  // C/D layout: col = lane&15, row = (lane>>4)*4 + r  [measured m89/m91]
  const int crow = (lane >> 4) << 2;
  const int ccol = lane & 15;
#pragma unroll
  for (int i = 0; i < 4; i++) {
#pragma unroll
    for (int j = 0; j < 4; j++) {
      const int gm = tile_m + wm + i * 16 + crow;
      const int gn = tile_n + wn + j * 16 + ccol;
      const float bv = bias[gn];
#pragma unroll
      for (int r = 0; r < 4; r++) {
        float v = acc[i][j][r] + bv;
        if (RELU) v = fmaxf(v, 0.f);
        if (OUTBF) ((u16*)Cout)[(size_t)(gm + r) * N + gn] = f2bf(v);
        else       ((float*)Cout)[(size_t)(gm + r) * N + gn] = v;
      }
    }
  }
}

// ---------------- scan_one: single-dispatch segmented scan with flag sync ----------
// q bf16 [2048][8192]; 64 segments x 32 t-steps; 512 blocks = 64 seg x 8 colgroups.
// Block (seg,g): loads its 32 q rows into REGISTERS (read q once), publishes segment
// carries (plain stores -> per-thread __threadfence -> __syncthreads -> lane0
// atomicExch flag), spins on the seg predecessor flags of its colgroup, folds their
// carries with AGENT-scope atomic loads (bypasses non-coherent per-XCD L2s), then
// rescans from registers and emits bf16 m. Deadlock-free: every block sets its flag
// before any wait, so no co-residency requirement.
#define SEG 32
#define NSEG 64

__global__ __launch_bounds__(256) void scan_one(const uint2* __restrict__ qb,
                                                float* __restrict__ carry,
                                                uint32_t* __restrict__ flags,
                                                const float* __restrict__ beta_arr,
                                                uint2* __restrict__ mb) {
  const int seg = blockIdx.x >> 3;
  const int g   = blockIdx.x & 7;
  const int cq  = g * 256 + threadIdx.x;  // [0,2048) channel quads (4 ch each)
  const int h0  = (cq * 4) & 1023;
  const float b0 = beta_arr[h0], b1 = beta_arr[h0 + 1];
  const float b2 = beta_arr[h0 + 2], b3 = beta_arr[h0 + 3];

  // ---- load q segment into registers (the only q read) ----
  uint2 qr[SEG];
  const uint2* p = qb + (size_t)seg * SEG * 2048 + cq;
#pragma unroll
  for (int t = 0; t < SEG; t++) qr[t] = p[(size_t)t * 2048];

  // ---- local carry (fp32 Horner) ----
  float c0 = 0.f, c1 = 0.f, c2 = 0.f, c3 = 0.f;
#pragma unroll
  for (int t = 0; t < SEG; t++) {
    c0 = fmaf(b0, c0, bf2f(qr[t].x & 0xffffu));
    c1 = fmaf(b1, c1, bf2f(qr[t].x >> 16));
    c2 = fmaf(b2, c2, bf2f(qr[t].y & 0xffffu));
    c3 = fmaf(b3, c3, bf2f(qr[t].y >> 16));
  }

  // ---- publish carries + flag ----
  {
    float* cw = carry + (size_t)seg * 8192 + (size_t)cq * 4;
    *(float4*)cw = make_float4(c0, c1, c2, c3);
  }
  __threadfence();        // per-thread: make my stores agent-visible (L2 writeback)
  __syncthreads();        // all threads fenced
  if (threadIdx.x == 0) atomicExch(&flags[blockIdx.x], 1u);

  // ---- wait for predecessors (same colgroup): flags[j*8+g], j < seg ----
  if ((int)threadIdx.x < seg) {
    while (__hip_atomic_load(&flags[threadIdx.x * 8 + g],
                             __ATOMIC_ACQUIRE, __HIP_MEMORY_SCOPE_AGENT) == 0) {}
  }
  __syncthreads();

  // ---- fold predecessor carries with ratio beta^32 (agent-scope loads) ----
  float s0 = b0, s1 = b1, s2 = b2, s3 = b3;
#pragma unroll
  for (int i = 0; i < 5; i++) { s0 *= s0; s1 *= s1; s2 *= s2; s3 *= s3; }
  float m0 = 0.f, m1 = 0.f, m2 = 0.f, m3 = 0.f;
  for (int j = 0; j < seg; j++) {  // uniform per block
    const float* cr = carry + (size_t)j * 8192 + (size_t)cq * 4;
    float v0 = __hip_atomic_load(cr + 0, __ATOMIC_RELAXED, __HIP_MEMORY_SCOPE_AGENT);
    float v1 = __hip_atomic_load(cr + 1, __ATOMIC_RELAXED, __HIP_MEMORY_SCOPE_AGENT);
    float v2 = __hip_atomic_load(cr + 2, __ATOMIC_RELAXED, __HIP_MEMORY_SCOPE_AGENT);
    float v3 = __hip_atomic_load(cr + 3, __ATOMIC_RELAXED, __HIP_MEMORY_SCOPE_AGENT);
    m0 = fmaf(s0, m0, v0); m1 = fmaf(s1, m1, v1);
    m2 = fmaf(s2, m2, v2); m3 = fmaf(s3, m3, v3);
  }

  // ---- rescan from registers, emit bf16 m ----
  uint2* o = mb + (size_t)seg * SEG * 2048 + cq;
#pragma unroll
  for (int t = 0; t < SEG; t++) {
    m0 = fmaf(b0, m0, bf2f(qr[t].x & 0xffffu));
    m1 = fmaf(b1, m1, bf2f(qr[t].x >> 16));
    m2 = fmaf(b2, m2, bf2f(qr[t].y & 0xffffu));
    m3 = fmaf(b3, m3, bf2f(qr[t].y >> 16));
    uint2 w;
    w.x = (uint32_t)f2bf(m0) | ((uint32_t)f2bf(m1) << 16);
    w.y = (uint32_t)f2bf(m2) | ((uint32_t)f2bf(m3) << 16);
    o[(size_t)t * 2048] = w;
  }
}

extern "C" void kernel_launch(void* const* d_in, const int* in_sizes, int n_in,
                              void* d_out, int out_size, void* d_ws, size_t ws_size,
                              hipStream_t stream) {
  const float* x        = (const float*)d_in[0];
  const float* W_q      = (const float*)d_in[1];
  const float* b_q      = (const float*)d_in[2];
  const float* beta_raw = (const float*)d_in[3];
  const float* W_fc     = (const float*)d_in[4];
  const float* b_fc     = (const float*)d_in[5];

  const int H = 1024;
  const int M = 2048 * 8;              // T*B = 16384 rows
  const size_t MH = (size_t)M * H;     // 16.7M elements

  char* ws = (char*)d_ws;
  u16* x_bf    = (u16*)ws;  ws += MH * 2;                   // 32 MB
  u16* q_bf    = (u16*)ws;  ws += MH * 2;                   // 32 MB
  u16* m_bf    = (u16*)ws;  ws += MH * 2;                   // 32 MB
  u16* wq_bf   = (u16*)ws;  ws += (size_t)H * H * 2;        // 2 MB
  u16* wfc_bf  = (u16*)ws;  ws += (size_t)H * H * 2;        // 2 MB
  float* beta  = (float*)ws; ws += 4096;
  float* carry = (float*)ws; ws += (size_t)NSEG * 8192 * 4; // 2 MB
  uint32_t* flags = (uint32_t*)ws; ws += 4096;

  prep_all<<<(int)(MH / 8 / 256), 256, 0, stream>>>(x, W_q, W_fc, beta_raw,
                                                    x_bf, wq_bf, wfc_bf, beta, flags);

  gemm_bt<0, 1><<<1024, 256, 0, stream>>>(x_bf, wq_bf, b_q, q_bf, M, H, H);

  scan_one<<<512, 256, 0, stream>>>((const uint2*)q_bf, carry, flags, beta,
                                    (uint2*)m_bf);

  gemm_bt<1, 0><<<1024, 256, 0, stream>>>(m_bf, wfc_bf, b_fc, d_out, M, H, H);
}